// Round 1
// 254.269 us; speedup vs baseline: 1.0604x; 1.0604x over previous
//
#include <hip/hip_runtime.h>
#include <math.h>

#define IMG_H 1024
#define IMG_W 1024
#define IMG_B 8
#define TPB 256                    // 256 thr * 4 px = one full row
#define RPB 16                     // output rows per band
#define BANDS (IMG_H / RPB)        // 64
#define NBLK (IMG_B * BANDS)       // 512 blocks = 2/CU

__device__ __forceinline__ float sig2(float x) {   // sigmoid(2x) == sigmoid(x/EPS)
    return 1.0f / (1.0f + __expf(-2.0f * x));
}

// ---------------------------------------------------------------------------
// Depth-2 fused kernel, 2 barriers/row (was 4).
// All y-direction deps are thread-local (register history); only the wave/
// thread boundary scalars (p0[x-1] for j==0, u[x+1] for j==3) go through LDS.
// Barrier A: after S1 (p0 boundary of row y).  Barrier B: after S3 (p0'
// boundary of row z).  S2/S5 read only values fenced by earlier barriers.
// ---------------------------------------------------------------------------
__global__ __launch_bounds__(TPB) void k_fused2(const float* __restrict__ qin,
                                                const float* __restrict__ vf,
                                                const float* __restrict__ o,
                                                float* __restrict__ qout) {
    __shared__ float sp0b[TPB + 1];      // p0_i[x0+3] per thread, row y   (single buf: B(y) fences reuse)
    __shared__ float su0b[2][TPB + 1];   // u_i[x0] per thread, row parity
    __shared__ float sp1b[TPB + 1];      // p0'[x0+3] per thread, row z    (single buf: A(y+1) fences reuse)
    __shared__ float su1b[2][TPB + 1];   // u'[x0] per thread, row parity

    const int img  = blockIdx.x / BANDS;
    const int r0   = (blockIdx.x % BANDS) * RPB;
    const int tid  = threadIdx.x;
    const int x0   = tid * 4;
    const bool topb = (r0 == 0);
    const size_t ibase = (size_t)img * IMG_H * IMG_W;

    if (tid == 0) {                      // left pad = 0, right pad = 0; set once
        sp0b[0] = 0.0f; sp1b[0] = 0.0f;
        su0b[0][TPB] = 0.0f; su0b[1][TPB] = 0.0f;
        su1b[0][TPB] = 0.0f; su1b[1][TPB] = 0.0f;
    }

    const int ylo  = topb ? 0 : r0 - 2;
    const int yhi  = (r0 + RPB + 1 < IMG_H) ? r0 + RPB + 1 : IMG_H - 1;
    const int yend = r0 + RPB + 1;
    const int u_lo = topb ? 0 : r0 - 1;

    float qc[4], oc4[4], v0c[4], v1c[4];                 // row y
    float qn[4], on4[4], v0n[4], v1n[4];                 // prefetch row y+1
    float p1prev[4] = {0,0,0,0};                         // p1_i at y-1
    float qz[4], oz4[4], v0z[4], v1z[4];                 // row y-1 inputs
    float v0w[4], v1w[4];                                // vf at row y-2
    float qpz[4], qpw[4];                                // q' at y-1, y-2
    float p0pz[4], p1pz[4];                              // p0'/p1' at y-1
    float p1pprev[4] = {0,0,0,0};                        // p1' at y-2
    float ucY[4] = {0,0,0,0}, ucZ[4] = {0,0,0,0};        // u_i rows y, y-1
    float u1Z[4] = {0,0,0,0}, u1W[4] = {0,0,0,0};        // u'  rows y-1, y-2

    // preload first row
    {
        const size_t rb = ibase + (size_t)ylo * IMG_W + x0;
        float4 q4 = *(const float4*)(qin + rb);
        float4 o4 = *(const float4*)(o + rb);
        const size_t vb = ((size_t)ylo * IMG_W + x0) * 2;
        float4 va = *(const float4*)(vf + vb);
        float4 vb4 = *(const float4*)(vf + vb + 4);
        qc[0]=q4.x; qc[1]=q4.y; qc[2]=q4.z; qc[3]=q4.w;
        oc4[0]=o4.x; oc4[1]=o4.y; oc4[2]=o4.z; oc4[3]=o4.w;
        v0c[0]=va.x; v0c[1]=va.z; v0c[2]=vb4.x; v0c[3]=vb4.z;
        v1c[0]=va.y; v1c[1]=va.w; v1c[2]=vb4.y; v1c[3]=vb4.w;
    }

    for (int y = ylo; y <= yend; ++y) {
        // prefetch row y+1
        if (y + 1 <= yhi) {
            const size_t rb = ibase + (size_t)(y + 1) * IMG_W + x0;
            float4 q4 = *(const float4*)(qin + rb);
            float4 o4 = *(const float4*)(o + rb);
            const size_t vb = ((size_t)(y + 1) * IMG_W + x0) * 2;
            float4 va = *(const float4*)(vf + vb);
            float4 vb4 = *(const float4*)(vf + vb + 4);
            qn[0]=q4.x; qn[1]=q4.y; qn[2]=q4.z; qn[3]=q4.w;
            on4[0]=o4.x; on4[1]=o4.y; on4[2]=o4.z; on4[3]=o4.w;
            v0n[0]=va.x; v0n[1]=va.z; v0n[2]=vb4.x; v0n[3]=vb4.z;
            v1n[0]=va.y; v1n[1]=va.w; v1n[2]=vb4.y; v1n[3]=vb4.w;
        } else {
#pragma unroll
            for (int j = 0; j < 4; ++j) { qn[j]=0.f; on4[j]=0.f; v0n[j]=0.f; v1n[j]=0.f; }
        }

        // ---- S1: p0/p1 of q_i row y; only boundary p0[3] -> LDS ----
        float p0c[4], p1c[4];
        const bool have_y = (y <= yhi);
        if (have_y) {
#pragma unroll
            for (int j = 0; j < 4; ++j) {
                p0c[j] = v0c[j] * qc[j];
                p1c[j] = v1c[j] * qc[j];
            }
            sp0b[tid + 1] = p0c[3];
        } else {
#pragma unroll
            for (int j = 0; j < 4; ++j) { p0c[j] = 0.f; p1c[j] = 0.f; }
        }
        __syncthreads();                                  // barrier A

        // ---- S2: u_i[y] -> registers (+ boundary u[0] -> LDS) ----
        const int yb = y & 1;
        if (y >= u_lo) {
            const float lft = sp0b[tid];                  // p0 at x0-1 (0 for tid 0)
#pragma unroll
            for (int j = 0; j < 4; ++j) {
                float pm1 = (j == 0) ? lft : p0c[j - 1];
                float Tq = p1c[j] - p1prev[j] + p0c[j] - pm1;
                ucY[j] = (y <= IMG_H - 1) ? sig2(oc4[j] - Tq) : 0.0f;
            }
            su0b[yb][tid] = ucY[0];
        }

        // ---- S3: q'[z], z = y-1 (gy thread-local, gx needs u[z][x+1] only at j==3) ----
        const int z = y - 1;
        const int zb = z & 1;
        const bool s3 = (z >= u_lo) && (z <= r0 + RPB) && (z <= IMG_H - 1);
        if (s3) {
            const float uR = su0b[zb][tid + 1];           // u_i[z][x0+4] (0 past right edge)
#pragma unroll
            for (int j = 0; j < 4; ++j) {
                float gy = ucY[j] - ucZ[j];
                float gx = ((j < 3) ? ucZ[j + 1] : uR) - ucZ[j];
                qpz[j] = fmaxf(qz[j] - 0.5f * (gy * v1z[j] + gx * v0z[j]), 0.0f);
            }
#pragma unroll
            for (int j = 0; j < 4; ++j) {
                p0pz[j] = v0z[j] * qpz[j];
                p1pz[j] = v1z[j] * qpz[j];
            }
            sp1b[tid + 1] = p0pz[3];
        }
        __syncthreads();                                  // barrier B

        // ---- S4: u'[z] -> registers (+ boundary -> LDS) ----
        if (z >= r0 && z <= r0 + RPB) {
            const float lft = sp1b[tid];
#pragma unroll
            for (int j = 0; j < 4; ++j) {
                float pm1 = (j == 0) ? lft : p0pz[j - 1];
                float Tq = p1pz[j] - p1pprev[j] + p0pz[j] - pm1;
                u1Z[j] = (z <= IMG_H - 1) ? sig2(oz4[j] - Tq) : 0.0f;
            }
            su1b[zb][tid] = u1Z[0];
        }

        // ---- S5: q''[w], w = y-2 -> global (all inputs register/fenced-LDS) ----
        const int w = y - 2;
        if (w >= r0 && w <= r0 + RPB - 1) {
            const int wb = w & 1;
            const float uR = su1b[wb][tid + 1];
            float r[4];
#pragma unroll
            for (int j = 0; j < 4; ++j) {
                float gy = u1Z[j] - u1W[j];
                float gx = ((j < 3) ? u1W[j + 1] : uR) - u1W[j];
                r[j] = fmaxf(qpw[j] - 0.5f * (gy * v1w[j] + gx * v0w[j]), 0.0f);
            }
            *(float4*)(qout + ibase + (size_t)w * IMG_W + x0) =
                make_float4(r[0], r[1], r[2], r[3]);
        }

        // ---- rotate ----
#pragma unroll
        for (int j = 0; j < 4; ++j) {
            p1prev[j] = p1c[j];
            v0w[j] = v0z[j]; v1w[j] = v1z[j];
            qz[j] = qc[j]; oz4[j] = oc4[j]; v0z[j] = v0c[j]; v1z[j] = v1c[j];
            qc[j] = qn[j]; oc4[j] = on4[j]; v0c[j] = v0n[j]; v1c[j] = v1n[j];
            ucZ[j] = ucY[j];
            u1W[j] = u1Z[j];
        }
        if (s3) {
#pragma unroll
            for (int j = 0; j < 4; ++j) { qpw[j] = qpz[j]; p1pprev[j] = p1pz[j]; }
        }
    }
}

// ---------------------------------------------------------------------------
// Init depth-2, 1 barrier/row (was 3): u0 = sig2(o) is fully thread-local.
// sp1b double-buffered by iteration parity (its read is post-barrier and the
// next write is pre-next-barrier — single buffer would race at wave seams).
// ---------------------------------------------------------------------------
__global__ __launch_bounds__(TPB) void k_init2(const float* __restrict__ o,
                                               const float* __restrict__ vf,
                                               float* __restrict__ qout) {
    __shared__ float su0b[2][TPB + 1];
    __shared__ float sp1b[2][TPB + 1];
    __shared__ float su1b[2][TPB + 1];

    const int img  = blockIdx.x / BANDS;
    const int r0   = (blockIdx.x % BANDS) * RPB;
    const int tid  = threadIdx.x;
    const int x0   = tid * 4;
    const bool topb = (r0 == 0);
    const size_t ibase = (size_t)img * IMG_H * IMG_W;

    if (tid == 0) {
        sp1b[0][0] = 0.0f; sp1b[1][0] = 0.0f;
        su0b[0][TPB] = 0.0f; su0b[1][TPB] = 0.0f;
        su1b[0][TPB] = 0.0f; su1b[1][TPB] = 0.0f;
    }

    const int u_lo = topb ? 0 : r0 - 1;
    const int ylo  = u_lo;
    const int yhi  = (r0 + RPB + 1 < IMG_H) ? r0 + RPB + 1 : IMG_H - 1;
    const int yend = r0 + RPB + 1;

    float oc4[4], v0c[4], v1c[4];
    float on4[4], v0n[4], v1n[4];
    float oz4[4], v0z[4], v1z[4];
    float v0w[4], v1w[4];
    float qpz[4], qpw[4];
    float p0pz[4], p1pz[4];
    float p1pprev[4] = {0,0,0,0};
    float ucY[4] = {0,0,0,0}, ucZ[4] = {0,0,0,0};
    float u1Z[4] = {0,0,0,0}, u1W[4] = {0,0,0,0};

    {
        const size_t rb = ibase + (size_t)ylo * IMG_W + x0;
        float4 o4 = *(const float4*)(o + rb);
        const size_t vb = ((size_t)ylo * IMG_W + x0) * 2;
        float4 va = *(const float4*)(vf + vb);
        float4 vb4 = *(const float4*)(vf + vb + 4);
        oc4[0]=o4.x; oc4[1]=o4.y; oc4[2]=o4.z; oc4[3]=o4.w;
        v0c[0]=va.x; v0c[1]=va.z; v0c[2]=vb4.x; v0c[3]=vb4.z;
        v1c[0]=va.y; v1c[1]=va.w; v1c[2]=vb4.y; v1c[3]=vb4.w;
    }

    for (int y = ylo; y <= yend; ++y) {
        if (y + 1 <= yhi) {
            const size_t rb = ibase + (size_t)(y + 1) * IMG_W + x0;
            float4 o4 = *(const float4*)(o + rb);
            const size_t vb = ((size_t)(y + 1) * IMG_W + x0) * 2;
            float4 va = *(const float4*)(vf + vb);
            float4 vb4 = *(const float4*)(vf + vb + 4);
            on4[0]=o4.x; on4[1]=o4.y; on4[2]=o4.z; on4[3]=o4.w;
            v0n[0]=va.x; v0n[1]=va.z; v0n[2]=vb4.x; v0n[3]=vb4.z;
            v1n[0]=va.y; v1n[1]=va.w; v1n[2]=vb4.y; v1n[3]=vb4.w;
        } else {
#pragma unroll
            for (int j = 0; j < 4; ++j) { on4[j]=0.f; v0n[j]=0.f; v1n[j]=0.f; }
        }

        // ---- S0: u0[y] = sig2(o[y]) (thread-local) ----
        const int yb = y & 1;
#pragma unroll
        for (int j = 0; j < 4; ++j)
            ucY[j] = (y <= IMG_H - 1) ? sig2(oc4[j]) : 0.0f;
        su0b[yb][tid] = ucY[0];

        // ---- S3: q1[z] = relu(-0.5*grad.u0) ----
        const int z = y - 1;
        const int zb = z & 1;
        const bool s3 = (z >= u_lo) && (z <= r0 + RPB) && (z <= IMG_H - 1);
        if (s3) {
            const float uR = su0b[zb][tid + 1];
#pragma unroll
            for (int j = 0; j < 4; ++j) {
                float gy = ucY[j] - ucZ[j];
                float gx = ((j < 3) ? ucZ[j + 1] : uR) - ucZ[j];
                qpz[j] = fmaxf(-0.5f * (gy * v1z[j] + gx * v0z[j]), 0.0f);
            }
#pragma unroll
            for (int j = 0; j < 4; ++j) {
                p0pz[j] = v0z[j] * qpz[j];
                p1pz[j] = v1z[j] * qpz[j];
            }
            sp1b[yb][tid + 1] = p0pz[3];
        }
        __syncthreads();                                  // the one barrier

        // ---- S4: u1[z] ----
        if (z >= r0 && z <= r0 + RPB) {
            const float lft = sp1b[yb][tid];
#pragma unroll
            for (int j = 0; j < 4; ++j) {
                float pm1 = (j == 0) ? lft : p0pz[j - 1];
                float Tq = p1pz[j] - p1pprev[j] + p0pz[j] - pm1;
                u1Z[j] = (z <= IMG_H - 1) ? sig2(oz4[j] - Tq) : 0.0f;
            }
            su1b[zb][tid] = u1Z[0];
        }

        // ---- S5: q2[w] -> global ----
        const int w = y - 2;
        if (w >= r0 && w <= r0 + RPB - 1) {
            const int wb = w & 1;
            const float uR = su1b[wb][tid + 1];
            float r[4];
#pragma unroll
            for (int j = 0; j < 4; ++j) {
                float gy = u1Z[j] - u1W[j];
                float gx = ((j < 3) ? u1W[j + 1] : uR) - u1W[j];
                r[j] = fmaxf(qpw[j] - 0.5f * (gy * v1w[j] + gx * v0w[j]), 0.0f);
            }
            *(float4*)(qout + ibase + (size_t)w * IMG_W + x0) =
                make_float4(r[0], r[1], r[2], r[3]);
        }

#pragma unroll
        for (int j = 0; j < 4; ++j) {
            v0w[j] = v0z[j]; v1w[j] = v1z[j];
            oz4[j] = oc4[j]; v0z[j] = v0c[j]; v1z[j] = v1c[j];
            oc4[j] = on4[j]; v0c[j] = v0n[j]; v1c[j] = v1n[j];
            ucZ[j] = ucY[j];
            u1W[j] = u1Z[j];
        }
        if (s3) {
#pragma unroll
            for (int j = 0; j < 4; ++j) { qpw[j] = qpz[j]; p1pprev[j] = p1pz[j]; }
        }
    }
}

// ---------------------------------------------------------------------------
// Final: out = 2*(o - Tq(q10)). One row per block; boundary-only LDS.
// ---------------------------------------------------------------------------
__global__ __launch_bounds__(TPB) void k_final(const float* __restrict__ q,
                                               const float* __restrict__ vf,
                                               const float* __restrict__ o,
                                               float* __restrict__ out) {
    __shared__ float sp0b[TPB + 1];
    const int row = blockIdx.x & (IMG_H - 1);
    const int tid = threadIdx.x;
    const int x0  = tid * 4;
    const size_t base = (size_t)blockIdx.x * IMG_W;

    float4 q4 = *(const float4*)(q + base + x0);
    const size_t vbase = ((size_t)row * IMG_W + x0) * 2;
    float4 vfa = *(const float4*)(vf + vbase);
    float4 vfb = *(const float4*)(vf + vbase + 4);

    const float v0[4] = {vfa.x, vfa.z, vfb.x, vfb.z};
    const float v1[4] = {vfa.y, vfa.w, vfb.y, vfb.w};
    const float qc[4] = {q4.x, q4.y, q4.z, q4.w};

    float p0[4], p1[4];
#pragma unroll
    for (int j = 0; j < 4; ++j) {
        p0[j] = v0[j] * qc[j];
        p1[j] = v1[j] * qc[j];
    }
    sp0b[tid + 1] = p0[3];
    if (tid == 0) sp0b[0] = 0.0f;

    float p1m[4];
    if (row > 0) {
        float4 qm  = *(const float4*)(q + base - IMG_W + x0);
        float4 vma = *(const float4*)(vf + vbase - 2 * IMG_W);
        float4 vmb = *(const float4*)(vf + vbase - 2 * IMG_W + 4);
        p1m[0] = qm.x * vma.y; p1m[1] = qm.y * vma.w;
        p1m[2] = qm.z * vmb.y; p1m[3] = qm.w * vmb.w;
    } else {
        p1m[0] = p1m[1] = p1m[2] = p1m[3] = 0.0f;
    }

    float4 o4 = *(const float4*)(o + base + x0);
    const float oc[4] = {o4.x, o4.y, o4.z, o4.w};

    __syncthreads();

    const float lft = sp0b[tid];
    float r[4];
#pragma unroll
    for (int j = 0; j < 4; ++j) {
        float pm1 = (j == 0) ? lft : p0[j - 1];
        float Tq = p1[j] - p1m[j] + p0[j] - pm1;
        r[j] = 2.0f * (oc[j] - Tq);
    }
    *(float4*)(out + base + x0) = make_float4(r[0], r[1], r[2], r[3]);
}

extern "C" void kernel_launch(void* const* d_in, const int* in_sizes, int n_in,
                              void* d_out, int out_size, void* d_ws, size_t ws_size,
                              hipStream_t stream) {
    const float* o  = (const float*)d_in[0];
    const float* vf = (const float*)d_in[1];

    float* qA = (float*)d_ws;    // q2, q6, q10
    float* qB = (float*)d_out;   // q4, q8 (overwritten by final output)

    k_init2 <<<NBLK, TPB, 0, stream>>>(o, vf, qA);        // q2 -> A
    k_fused2<<<NBLK, TPB, 0, stream>>>(qA, vf, o, qB);    // q4 -> B
    k_fused2<<<NBLK, TPB, 0, stream>>>(qB, vf, o, qA);    // q6 -> A
    k_fused2<<<NBLK, TPB, 0, stream>>>(qA, vf, o, qB);    // q8 -> B
    k_fused2<<<NBLK, TPB, 0, stream>>>(qB, vf, o, qA);    // q10 -> A
    k_final <<<IMG_B * IMG_H, TPB, 0, stream>>>(qA, vf, o, (float*)d_out);
}

// Round 2
// 251.175 us; speedup vs baseline: 1.0735x; 1.0123x over previous
//
#include <hip/hip_runtime.h>
#include <math.h>

#define IMG_H 1024
#define IMG_W 1024
#define IMG_B 8
#define TPB 256                    // 256 thr * 4 px = one full row
#define RPB 16                     // output rows per band
#define BANDS (IMG_H / RPB)        // 64
#define NBLK (IMG_B * BANDS)       // 512 blocks = 2/CU

__device__ __forceinline__ float sig2(float x) {   // sigmoid(2x) == sigmoid(x/EPS)
    return 1.0f / (1.0f + __expf(-2.0f * x));
}
__device__ __forceinline__ int imax(int a, int b) { return a > b ? a : b; }
__device__ __forceinline__ int imin(int a, int b) { return a < b ? a : b; }

// ---------------------------------------------------------------------------
// Generic depth-D row-pipelined kernel.
//   READQ: level-0 u comes from sig2(o - Tq(qin)); else u0 = sig2(o) (q0=0).
//   FINAL: after Q-stage D, compute out = 2*(o - Tq(q^D)) and write that
//          instead of writing q^D (adds 1 halo row + 1 barrier/step).
// Level l (1..D): q^l[t] = relu(q^{l-1}[t] - 0.5*(gy(u^{l-1})*v1 + gx*v0)),
//   gy[t] = u[t+1]-u[t] (register history), gx[t][x] = u[t][x+1]-u[t][x]
//   (3 of 4 in-thread, boundary via su).  U-stage l: u^l = sig2(o - Tq(q^l)),
//   Tq = p1[t]-p1[t-1] (register history) + p0[x]-p0[x-1] (boundary via sp).
// One barrier per level that does a p0 x-exchange; all other cross-thread
// reads are fenced by earlier barriers (parity double-buffer on su).
// ---------------------------------------------------------------------------
template<int D, bool READQ, bool FINAL>
__global__ __launch_bounds__(TPB, 2) void k_pipe(const float* __restrict__ qin,
                                                 const float* __restrict__ vf,
                                                 const float* __restrict__ o,
                                                 float* __restrict__ out) {
    __shared__ float sp[D + 1][TPB + 1];   // p0 boundary (level0 iff READQ, level D iff FINAL)
    __shared__ float su[D][2][TPB + 1];    // u boundary, row-parity double buffered

    const int img = blockIdx.x / BANDS;
    const int r0  = (blockIdx.x % BANDS) * RPB;
    const int tid = threadIdx.x;
    const int x0  = tid * 4;
    const size_t ibase = (size_t)img * IMG_H * IMG_W;

    if (tid == 0) {
#pragma unroll
        for (int l = 0; l <= D; ++l) sp[l][0] = 0.0f;
#pragma unroll
        for (int l = 0; l < D; ++l) { su[l][0][TPB] = 0.0f; su[l][1][TPB] = 0.0f; }
    }

    constexpr int HALO = FINAL ? 1 : 0;
    constexpr int NOH  = FINAL ? D + 1 : D;

    const int u0lo = imax(r0 - (D - 1) - HALO, 0);
    const int ylo  = READQ ? imax(r0 - D - HALO, 0) : u0lo;
    const int yend = r0 + RPB - 1 + D;
    const int yhi  = imin(yend, IMG_H - 1);

    float qc[4], qn[4], qz[4];             // q^0 rows y, y+1(prefetch), y-1
    float oh[NOH][4], on[4];               // o rows y-l
    float v0h[D + 1][4], v1h[D + 1][4], v0n[4], v1n[4];
    float uY[D][4], uZ[D][4];              // u^l rows y-l, y-l-1
    float p1prev[D + 1][4];                // p1 of q^l at previous row
    float qsave[D][4];                     // q^l held one step for level l+1
    float qvPrev[4];

#pragma unroll
    for (int j = 0; j < 4; ++j) {
        qc[j]=qn[j]=qz[j]=on[j]=v0n[j]=v1n[j]=qvPrev[j]=0.0f;
#pragma unroll
        for (int l = 0; l < NOH; ++l) oh[l][j] = 0.0f;
#pragma unroll
        for (int l = 0; l <= D; ++l) { v0h[l][j]=0.0f; v1h[l][j]=0.0f; p1prev[l][j]=0.0f; }
#pragma unroll
        for (int l = 0; l < D; ++l) { uY[l][j]=0.0f; uZ[l][j]=0.0f; qsave[l][j]=0.0f; }
    }

    // preload row ylo
    {
        const size_t rb = ibase + (size_t)ylo * IMG_W + x0;
        if constexpr (READQ) {
            float4 q4 = *(const float4*)(qin + rb);
            qc[0]=q4.x; qc[1]=q4.y; qc[2]=q4.z; qc[3]=q4.w;
        }
        float4 o4 = *(const float4*)(o + rb);
        oh[0][0]=o4.x; oh[0][1]=o4.y; oh[0][2]=o4.z; oh[0][3]=o4.w;
        const size_t vb = ((size_t)ylo * IMG_W + x0) * 2;
        float4 va = *(const float4*)(vf + vb);
        float4 vb4 = *(const float4*)(vf + vb + 4);
        v0h[0][0]=va.x; v0h[0][1]=va.z; v0h[0][2]=vb4.x; v0h[0][3]=vb4.z;
        v1h[0][0]=va.y; v1h[0][1]=va.w; v1h[0][2]=vb4.y; v1h[0][3]=vb4.w;
    }

    for (int y = ylo; y <= yend; ++y) {
        // ---- prefetch row y+1 ----
        if (y + 1 <= yhi) {
            const size_t rb = ibase + (size_t)(y + 1) * IMG_W + x0;
            if constexpr (READQ) {
                float4 q4 = *(const float4*)(qin + rb);
                qn[0]=q4.x; qn[1]=q4.y; qn[2]=q4.z; qn[3]=q4.w;
            }
            float4 o4 = *(const float4*)(o + rb);
            on[0]=o4.x; on[1]=o4.y; on[2]=o4.z; on[3]=o4.w;
            const size_t vb = ((size_t)(y + 1) * IMG_W + x0) * 2;
            float4 va = *(const float4*)(vf + vb);
            float4 vb4 = *(const float4*)(vf + vb + 4);
            v0n[0]=va.x; v0n[1]=va.z; v0n[2]=vb4.x; v0n[3]=vb4.z;
            v1n[0]=va.y; v1n[1]=va.w; v1n[2]=vb4.y; v1n[3]=vb4.w;
        } else {
#pragma unroll
            for (int j = 0; j < 4; ++j) { qn[j]=0.f; on[j]=0.f; v0n[j]=0.f; v1n[j]=0.f; }
        }

        // ---- level 0 ----
        if constexpr (READQ) {
            float p0c[4], p1c[4];
            const bool haveY = (y <= yhi);
            if (haveY) {
#pragma unroll
                for (int j = 0; j < 4; ++j) { p0c[j]=v0h[0][j]*qc[j]; p1c[j]=v1h[0][j]*qc[j]; }
                sp[0][tid + 1] = p0c[3];
            } else {
#pragma unroll
                for (int j = 0; j < 4; ++j) { p0c[j]=0.f; p1c[j]=0.f; }
            }
            __syncthreads();                       // barrier level 0
            if (y >= u0lo) {
                const float lft = sp[0][tid];
#pragma unroll
                for (int j = 0; j < 4; ++j) {
                    float pm1 = (j == 0) ? lft : p0c[j - 1];
                    float nu = (y <= IMG_H - 1)
                        ? sig2(oh[0][j] - (p1c[j] - p1prev[0][j] + p0c[j] - pm1)) : 0.0f;
                    uZ[0][j] = uY[0][j]; uY[0][j] = nu;
                }
                su[0][y & 1][tid] = uY[0][0];
            }
#pragma unroll
            for (int j = 0; j < 4; ++j) p1prev[0][j] = p1c[j];
        } else {
#pragma unroll
            for (int j = 0; j < 4; ++j) {
                float nu = (y <= IMG_H - 1) ? sig2(oh[0][j]) : 0.0f;
                uZ[0][j] = uY[0][j]; uY[0][j] = nu;
            }
            su[0][y & 1][tid] = uY[0][0];
        }

        // ---- levels 1..D ----
#pragma unroll
        for (int l = 1; l <= D; ++l) {
            const int t = y - l;
            const int qlo = imax(r0 - (D - l) - HALO, 0);
            const bool qvalid = (t >= qlo) && (t <= IMG_H - 1);
            float qbase[4], qv[4];
#pragma unroll
            for (int j = 0; j < 4; ++j)
                qbase[j] = (l == 1) ? (READQ ? qz[j] : 0.0f) : qsave[l - 1][j];
            if (l >= 2) {                           // delayed save (read-before-write)
#pragma unroll
                for (int j = 0; j < 4; ++j) qsave[l - 1][j] = qvPrev[j];
            }
            if (qvalid) {
                const float uR = su[l - 1][t & 1][tid + 1];
#pragma unroll
                for (int j = 0; j < 4; ++j) {
                    float gy = uY[l - 1][j] - uZ[l - 1][j];
                    float gx = ((j < 3) ? uZ[l - 1][j + 1] : uR) - uZ[l - 1][j];
                    qv[j] = fmaxf(qbase[j] - 0.5f * (gy * v1h[l][j] + gx * v0h[l][j]), 0.0f);
                }
            } else {
#pragma unroll
                for (int j = 0; j < 4; ++j) qv[j] = 0.0f;
            }

            if (l < D) {
                float p0p[4], p1p[4];
                if (qvalid) {
#pragma unroll
                    for (int j = 0; j < 4; ++j) { p0p[j]=v0h[l][j]*qv[j]; p1p[j]=v1h[l][j]*qv[j]; }
                    sp[l][tid + 1] = p0p[3];
                } else {
#pragma unroll
                    for (int j = 0; j < 4; ++j) { p0p[j]=0.f; p1p[j]=0.f; }
                }
                __syncthreads();                   // barrier level l
                const int ulo = imax(r0 - (D - 1 - l) - HALO, 0);
                if (t >= ulo) {
                    const float lft = sp[l][tid];
#pragma unroll
                    for (int j = 0; j < 4; ++j) {
                        float pm1 = (j == 0) ? lft : p0p[j - 1];
                        float nu = (t <= IMG_H - 1)
                            ? sig2(oh[l][j] - (p1p[j] - p1prev[l][j] + p0p[j] - pm1)) : 0.0f;
                        uZ[l][j] = uY[l][j]; uY[l][j] = nu;
                    }
                    su[l][t & 1][tid] = uY[l][0];
                }
#pragma unroll
                for (int j = 0; j < 4; ++j) p1prev[l][j] = p1p[j];
            } else {
                if constexpr (FINAL) {
                    float p0p[4], p1p[4];
                    if (qvalid) {
#pragma unroll
                        for (int j = 0; j < 4; ++j) { p0p[j]=v0h[D][j]*qv[j]; p1p[j]=v1h[D][j]*qv[j]; }
                        sp[D][tid + 1] = p0p[3];
                    } else {
#pragma unroll
                        for (int j = 0; j < 4; ++j) { p0p[j]=0.f; p1p[j]=0.f; }
                    }
                    __syncthreads();               // barrier final
                    if (t >= r0 && t < r0 + RPB) {
                        const float lft = sp[D][tid];
                        float r[4];
#pragma unroll
                        for (int j = 0; j < 4; ++j) {
                            float pm1 = (j == 0) ? lft : p0p[j - 1];
                            float Tq = p1p[j] - p1prev[D][j] + p0p[j] - pm1;
                            r[j] = 2.0f * (oh[D][j] - Tq);
                        }
                        *(float4*)(out + ibase + (size_t)t * IMG_W + x0) =
                            make_float4(r[0], r[1], r[2], r[3]);
                    }
#pragma unroll
                    for (int j = 0; j < 4; ++j) p1prev[D][j] = p1p[j];
                } else {
                    if (t >= r0 && t < r0 + RPB) {
                        *(float4*)(out + ibase + (size_t)t * IMG_W + x0) =
                            make_float4(qv[0], qv[1], qv[2], qv[3]);
                    }
                }
            }
#pragma unroll
            for (int j = 0; j < 4; ++j) qvPrev[j] = qv[j];
        }

        // ---- rotate row histories ----
#pragma unroll
        for (int k = D; k >= 1; --k)
#pragma unroll
            for (int j = 0; j < 4; ++j) { v0h[k][j]=v0h[k-1][j]; v1h[k][j]=v1h[k-1][j]; }
#pragma unroll
        for (int j = 0; j < 4; ++j) { v0h[0][j]=v0n[j]; v1h[0][j]=v1n[j]; }
#pragma unroll
        for (int k = NOH - 1; k >= 1; --k)
#pragma unroll
            for (int j = 0; j < 4; ++j) oh[k][j] = oh[k-1][j];
#pragma unroll
        for (int j = 0; j < 4; ++j) oh[0][j] = on[j];
        if constexpr (READQ) {
#pragma unroll
            for (int j = 0; j < 4; ++j) { qz[j] = qc[j]; qc[j] = qn[j]; }
        }
    }
}

extern "C" void kernel_launch(void* const* d_in, const int* in_sizes, int n_in,
                              void* d_out, int out_size, void* d_ws, size_t ws_size,
                              hipStream_t stream) {
    const float* o  = (const float*)d_in[0];
    const float* vf = (const float*)d_in[1];
    float* qA = (float*)d_ws;

    // iterations 1..5: o,vf -> q5  (no q read)
    k_pipe<5, false, false><<<NBLK, TPB, 0, stream>>>(o, vf, o, qA);
    // iterations 6..10 + final: q5,o,vf -> out
    k_pipe<5, true,  true ><<<NBLK, TPB, 0, stream>>>(qA, vf, o, (float*)d_out);
}

// Round 3
// 229.059 us; speedup vs baseline: 1.1771x; 1.0966x over previous
//
#include <hip/hip_runtime.h>
#include <math.h>

#define IMG_H 1024
#define IMG_W 1024
#define IMG_B 8
#define TPB 512                    // 512 thr * 2 px = one full row
#define PXT 2                      // pixels per thread
#define RPB 16                     // output rows per band
#define BANDS (IMG_H / RPB)        // 64
#define NBLK (IMG_B * BANDS)       // 512 blocks = 2/CU, 16 waves/CU

__device__ __forceinline__ float sig2(float x) {   // sigmoid(2x) == sigmoid(x/EPS)
    return 1.0f / (1.0f + __expf(-2.0f * x));
}
__device__ __forceinline__ int imax(int a, int b) { return a > b ? a : b; }
__device__ __forceinline__ int imin(int a, int b) { return a < b ? a : b; }

// ---------------------------------------------------------------------------
// Generic depth-D row-pipelined kernel, 2 px/thread for occupancy.
//   READQ: level-0 u comes from sig2(o - Tq(qin)); else u0 = sig2(o) (q0=0).
//   FINAL: after Q-stage D, compute out = 2*(o - Tq(q^D)) instead of q^D.
// All y-deps in register history; only per-thread boundary scalars cross
// threads via LDS (one barrier per p0-exchanging level).
// ---------------------------------------------------------------------------
template<int D, bool READQ, bool FINAL>
__global__ __launch_bounds__(TPB, 4) void k_pipe(const float* __restrict__ qin,
                                                 const float* __restrict__ vf,
                                                 const float* __restrict__ o,
                                                 float* __restrict__ out) {
    __shared__ float sp[D + 1][TPB + 1];   // p0 boundary
    __shared__ float su[D][2][TPB + 1];    // u boundary, row-parity double buffered

    const int img = blockIdx.x / BANDS;
    const int r0  = (blockIdx.x % BANDS) * RPB;
    const int tid = threadIdx.x;
    const int x0  = tid * PXT;
    const size_t ibase = (size_t)img * IMG_H * IMG_W;

    if (tid == 0) {
#pragma unroll
        for (int l = 0; l <= D; ++l) sp[l][0] = 0.0f;
#pragma unroll
        for (int l = 0; l < D; ++l) { su[l][0][TPB] = 0.0f; su[l][1][TPB] = 0.0f; }
    }

    constexpr int HALO = FINAL ? 1 : 0;
    constexpr int NOH  = FINAL ? D + 1 : D;

    const int u0lo = imax(r0 - (D - 1) - HALO, 0);
    const int ylo  = READQ ? imax(r0 - D - HALO, 0) : u0lo;
    const int yend = r0 + RPB - 1 + D;
    const int yhi  = imin(yend, IMG_H - 1);

    float qc[PXT], qn[PXT], qz[PXT];       // q^0 rows y, y+1(prefetch), y-1
    float oh[NOH][PXT], on[PXT];           // o rows y-l
    float v0h[D + 1][PXT], v1h[D + 1][PXT], v0n[PXT], v1n[PXT];
    float uY[D][PXT], uZ[D][PXT];          // u^l rows y-l, y-l-1
    float p1prev[D + 1][PXT];              // p1 of q^l at previous row
    float qsave[D][PXT];                   // q^l held one step for level l+1
    float qvPrev[PXT];

#pragma unroll
    for (int j = 0; j < PXT; ++j) {
        qc[j]=qn[j]=qz[j]=on[j]=v0n[j]=v1n[j]=qvPrev[j]=0.0f;
#pragma unroll
        for (int l = 0; l < NOH; ++l) oh[l][j] = 0.0f;
#pragma unroll
        for (int l = 0; l <= D; ++l) { v0h[l][j]=0.0f; v1h[l][j]=0.0f; p1prev[l][j]=0.0f; }
#pragma unroll
        for (int l = 0; l < D; ++l) { uY[l][j]=0.0f; uZ[l][j]=0.0f; qsave[l][j]=0.0f; }
    }

    // preload row ylo
    {
        const size_t rb = ibase + (size_t)ylo * IMG_W + x0;
        if constexpr (READQ) {
            float2 q2 = *(const float2*)(qin + rb);
            qc[0]=q2.x; qc[1]=q2.y;
        }
        float2 o2 = *(const float2*)(o + rb);
        oh[0][0]=o2.x; oh[0][1]=o2.y;
        const size_t vb = ((size_t)ylo * IMG_W + x0) * 2;
        float4 va = *(const float4*)(vf + vb);
        v0h[0][0]=va.x; v1h[0][0]=va.y; v0h[0][1]=va.z; v1h[0][1]=va.w;
    }

    for (int y = ylo; y <= yend; ++y) {
        // ---- prefetch row y+1 ----
        if (y + 1 <= yhi) {
            const size_t rb = ibase + (size_t)(y + 1) * IMG_W + x0;
            if constexpr (READQ) {
                float2 q2 = *(const float2*)(qin + rb);
                qn[0]=q2.x; qn[1]=q2.y;
            }
            float2 o2 = *(const float2*)(o + rb);
            on[0]=o2.x; on[1]=o2.y;
            const size_t vb = ((size_t)(y + 1) * IMG_W + x0) * 2;
            float4 va = *(const float4*)(vf + vb);
            v0n[0]=va.x; v1n[0]=va.y; v0n[1]=va.z; v1n[1]=va.w;
        } else {
#pragma unroll
            for (int j = 0; j < PXT; ++j) { qn[j]=0.f; on[j]=0.f; v0n[j]=0.f; v1n[j]=0.f; }
        }

        // ---- level 0 ----
        if constexpr (READQ) {
            float p0c[PXT], p1c[PXT];
            const bool haveY = (y <= yhi);
            if (haveY) {
#pragma unroll
                for (int j = 0; j < PXT; ++j) { p0c[j]=v0h[0][j]*qc[j]; p1c[j]=v1h[0][j]*qc[j]; }
                sp[0][tid + 1] = p0c[PXT - 1];
            } else {
#pragma unroll
                for (int j = 0; j < PXT; ++j) { p0c[j]=0.f; p1c[j]=0.f; }
            }
            __syncthreads();                       // barrier level 0
            if (y >= u0lo) {
                const float lft = sp[0][tid];
#pragma unroll
                for (int j = 0; j < PXT; ++j) {
                    float pm1 = (j == 0) ? lft : p0c[j - 1];
                    float nu = (y <= IMG_H - 1)
                        ? sig2(oh[0][j] - (p1c[j] - p1prev[0][j] + p0c[j] - pm1)) : 0.0f;
                    uZ[0][j] = uY[0][j]; uY[0][j] = nu;
                }
                su[0][y & 1][tid] = uY[0][0];
            }
#pragma unroll
            for (int j = 0; j < PXT; ++j) p1prev[0][j] = p1c[j];
        } else {
#pragma unroll
            for (int j = 0; j < PXT; ++j) {
                float nu = (y <= IMG_H - 1) ? sig2(oh[0][j]) : 0.0f;
                uZ[0][j] = uY[0][j]; uY[0][j] = nu;
            }
            su[0][y & 1][tid] = uY[0][0];
        }

        // ---- levels 1..D ----
#pragma unroll
        for (int l = 1; l <= D; ++l) {
            const int t = y - l;
            const int qlo = imax(r0 - (D - l) - HALO, 0);
            const bool qvalid = (t >= qlo) && (t <= IMG_H - 1);
            float qbase[PXT], qv[PXT];
#pragma unroll
            for (int j = 0; j < PXT; ++j)
                qbase[j] = (l == 1) ? (READQ ? qz[j] : 0.0f) : qsave[l - 1][j];
            if (l >= 2) {                           // delayed save (read-before-write)
#pragma unroll
                for (int j = 0; j < PXT; ++j) qsave[l - 1][j] = qvPrev[j];
            }
            if (qvalid) {
                const float uR = su[l - 1][t & 1][tid + 1];
#pragma unroll
                for (int j = 0; j < PXT; ++j) {
                    float gy = uY[l - 1][j] - uZ[l - 1][j];
                    float gx = ((j < PXT - 1) ? uZ[l - 1][j + 1] : uR) - uZ[l - 1][j];
                    qv[j] = fmaxf(qbase[j] - 0.5f * (gy * v1h[l][j] + gx * v0h[l][j]), 0.0f);
                }
            } else {
#pragma unroll
                for (int j = 0; j < PXT; ++j) qv[j] = 0.0f;
            }

            if (l < D) {
                float p0p[PXT], p1p[PXT];
                if (qvalid) {
#pragma unroll
                    for (int j = 0; j < PXT; ++j) { p0p[j]=v0h[l][j]*qv[j]; p1p[j]=v1h[l][j]*qv[j]; }
                    sp[l][tid + 1] = p0p[PXT - 1];
                } else {
#pragma unroll
                    for (int j = 0; j < PXT; ++j) { p0p[j]=0.f; p1p[j]=0.f; }
                }
                __syncthreads();                   // barrier level l
                const int ulo = imax(r0 - (D - 1 - l) - HALO, 0);
                if (t >= ulo) {
                    const float lft = sp[l][tid];
#pragma unroll
                    for (int j = 0; j < PXT; ++j) {
                        float pm1 = (j == 0) ? lft : p0p[j - 1];
                        float nu = (t <= IMG_H - 1)
                            ? sig2(oh[l][j] - (p1p[j] - p1prev[l][j] + p0p[j] - pm1)) : 0.0f;
                        uZ[l][j] = uY[l][j]; uY[l][j] = nu;
                    }
                    su[l][t & 1][tid] = uY[l][0];
                }
#pragma unroll
                for (int j = 0; j < PXT; ++j) p1prev[l][j] = p1p[j];
            } else {
                if constexpr (FINAL) {
                    float p0p[PXT], p1p[PXT];
                    if (qvalid) {
#pragma unroll
                        for (int j = 0; j < PXT; ++j) { p0p[j]=v0h[D][j]*qv[j]; p1p[j]=v1h[D][j]*qv[j]; }
                        sp[D][tid + 1] = p0p[PXT - 1];
                    } else {
#pragma unroll
                        for (int j = 0; j < PXT; ++j) { p0p[j]=0.f; p1p[j]=0.f; }
                    }
                    __syncthreads();               // barrier final
                    if (t >= r0 && t < r0 + RPB) {
                        const float lft = sp[D][tid];
                        float r[PXT];
#pragma unroll
                        for (int j = 0; j < PXT; ++j) {
                            float pm1 = (j == 0) ? lft : p0p[j - 1];
                            float Tq = p1p[j] - p1prev[D][j] + p0p[j] - pm1;
                            r[j] = 2.0f * (oh[D][j] - Tq);
                        }
                        *(float2*)(out + ibase + (size_t)t * IMG_W + x0) =
                            make_float2(r[0], r[1]);
                    }
#pragma unroll
                    for (int j = 0; j < PXT; ++j) p1prev[D][j] = p1p[j];
                } else {
                    if (t >= r0 && t < r0 + RPB) {
                        *(float2*)(out + ibase + (size_t)t * IMG_W + x0) =
                            make_float2(qv[0], qv[1]);
                    }
                }
            }
#pragma unroll
            for (int j = 0; j < PXT; ++j) qvPrev[j] = qv[j];
        }

        // ---- rotate row histories ----
#pragma unroll
        for (int k = D; k >= 1; --k)
#pragma unroll
            for (int j = 0; j < PXT; ++j) { v0h[k][j]=v0h[k-1][j]; v1h[k][j]=v1h[k-1][j]; }
#pragma unroll
        for (int j = 0; j < PXT; ++j) { v0h[0][j]=v0n[j]; v1h[0][j]=v1n[j]; }
#pragma unroll
        for (int k = NOH - 1; k >= 1; --k)
#pragma unroll
            for (int j = 0; j < PXT; ++j) oh[k][j] = oh[k-1][j];
#pragma unroll
        for (int j = 0; j < PXT; ++j) oh[0][j] = on[j];
        if constexpr (READQ) {
#pragma unroll
            for (int j = 0; j < PXT; ++j) { qz[j] = qc[j]; qc[j] = qn[j]; }
        }
    }
}

extern "C" void kernel_launch(void* const* d_in, const int* in_sizes, int n_in,
                              void* d_out, int out_size, void* d_ws, size_t ws_size,
                              hipStream_t stream) {
    const float* o  = (const float*)d_in[0];
    const float* vf = (const float*)d_in[1];
    float* qA = (float*)d_ws;

    // iterations 1..5: o,vf -> q5  (no q read)
    k_pipe<5, false, false><<<NBLK, TPB, 0, stream>>>(o, vf, o, qA);
    // iterations 6..10 + final: q5,o,vf -> out
    k_pipe<5, true,  true ><<<NBLK, TPB, 0, stream>>>(qA, vf, o, (float*)d_out);
}

// Round 4
// 217.963 us; speedup vs baseline: 1.2371x; 1.0509x over previous
//
#include <hip/hip_runtime.h>
#include <math.h>

#define IMG_H 1024
#define IMG_W 1024
#define IMG_B 8
#define TPB 1024                   // 1024 thr * 1 px = one full row
#define RPB 16                     // output rows per band
#define BANDS (IMG_H / RPB)        // 64
#define NBLK (IMG_B * BANDS)       // 512 blocks = 2/CU = 32 waves/CU

__device__ __forceinline__ float sig2(float x) {   // sigmoid(2x) == sigmoid(x/EPS)
    return 1.0f / (1.0f + __expf(-2.0f * x));
}
__device__ __forceinline__ int imax(int a, int b) { return a > b ? a : b; }
__device__ __forceinline__ int imin(int a, int b) { return a < b ? a : b; }

// ---------------------------------------------------------------------------
// Depth-D row-pipelined kernel, 1 px/thread, 2 blocks/CU * 16 waves = 100% occ.
//   READQ: level-0 u = sig2(o - Tq(qin)); else u0 = sig2(o)  (q0 = 0).
//   FINAL: after Q-stage D, write out = 2*(o - Tq(q^D)) instead of q^D.
// All y-deps in per-thread register history; x-neighbor scalars cross threads
// via LDS. sp (p0 exchange) is shared across levels with level-parity double
// buffering: level l writes sp[l&1]; reuse of a buffer is 2 levels later,
// always separated by the intervening level's barrier.
// su (u rows) is per-level, row-parity double buffered.
// ---------------------------------------------------------------------------
template<int D, bool READQ, bool FINAL>
__global__ __launch_bounds__(TPB, 8) void k_pipe(const float* __restrict__ qin,
                                                 const float* __restrict__ vf,
                                                 const float* __restrict__ o,
                                                 float* __restrict__ out) {
    __shared__ float sp[2][TPB + 1];       // p0 boundary, level-parity
    __shared__ float su[D][2][TPB + 1];    // u rows, row-parity

    const int img = blockIdx.x / BANDS;
    const int r0  = (blockIdx.x % BANDS) * RPB;
    const int tid = threadIdx.x;
    const size_t ibase = (size_t)img * IMG_H * IMG_W;

    if (tid == 0) {
        sp[0][0] = 0.0f; sp[1][0] = 0.0f;
#pragma unroll
        for (int l = 0; l < D; ++l) { su[l][0][TPB] = 0.0f; su[l][1][TPB] = 0.0f; }
    }

    constexpr int HALO = FINAL ? 1 : 0;
    constexpr int NOH  = FINAL ? D + 1 : D;

    const int u0lo = imax(r0 - (D - 1) - HALO, 0);
    const int ylo  = READQ ? imax(r0 - D - HALO, 0) : u0lo;
    const int yend = r0 + RPB - 1 + D;
    const int yhi  = imin(yend, IMG_H - 1);

    float qc = 0.0f, qz = 0.0f;            // q^0 rows y, y-1
    float oh[NOH];                         // o rows y-l
    float v0h[D + 1], v1h[D + 1];          // vf rows y-l
    float uY[D], uZ[D];                    // u^l rows y-l, y-l-1
    float p1prev[D + 1];                   // p1 of q^l at previous row
    float qsave[D];                        // q^l held one step for level l+1
    float qvPrev = 0.0f;

#pragma unroll
    for (int l = 0; l < NOH; ++l) oh[l] = 0.0f;
#pragma unroll
    for (int l = 0; l <= D; ++l) { v0h[l] = 0.0f; v1h[l] = 0.0f; p1prev[l] = 0.0f; }
#pragma unroll
    for (int l = 0; l < D; ++l) { uY[l] = 0.0f; uZ[l] = 0.0f; qsave[l] = 0.0f; }

    const float* pQ = qin + ibase + (size_t)ylo * IMG_W + tid;
    const float* pO = o   + ibase + (size_t)ylo * IMG_W + tid;
    const float* pV = vf  + ((size_t)ylo * IMG_W + tid) * 2;

    for (int y = ylo; y <= yend; ++y) {
        // ---- shift row histories, then load row y ----
#pragma unroll
        for (int k = NOH - 1; k >= 1; --k) oh[k] = oh[k - 1];
#pragma unroll
        for (int k = D; k >= 1; --k) { v0h[k] = v0h[k - 1]; v1h[k] = v1h[k - 1]; }
        if constexpr (READQ) qz = qc;

        if (y <= yhi) {
            if constexpr (READQ) { qc = *pQ; pQ += IMG_W; }
            oh[0] = *pO; pO += IMG_W;
            float2 v2 = *(const float2*)pV; pV += 2 * IMG_W;
            v0h[0] = v2.x; v1h[0] = v2.y;
        } else {
            qc = 0.0f; oh[0] = 0.0f; v0h[0] = 0.0f; v1h[0] = 0.0f;
        }

        // ---- level 0 ----
        if constexpr (READQ) {
            float p0c = v0h[0] * qc;
            float p1c = v1h[0] * qc;
            sp[0][tid + 1] = p0c;
            __syncthreads();                       // barrier level 0
            if (y >= u0lo) {
                float pm1 = sp[0][tid];
                float nu = (y <= IMG_H - 1)
                    ? sig2(oh[0] - (p1c - p1prev[0] + p0c - pm1)) : 0.0f;
                uZ[0] = uY[0]; uY[0] = nu;
                su[0][y & 1][tid] = nu;
            }
            p1prev[0] = p1c;
        } else {
            float nu = (y <= IMG_H - 1) ? sig2(oh[0]) : 0.0f;
            uZ[0] = uY[0]; uY[0] = nu;
            su[0][y & 1][tid] = nu;
        }

        // ---- levels 1..D ----
#pragma unroll
        for (int l = 1; l <= D; ++l) {
            const int t = y - l;
            const int qlo = imax(r0 - (D - l) - HALO, 0);
            const bool qvalid = (t >= qlo) && (t <= IMG_H - 1);
            float qbase = (l == 1) ? (READQ ? qz : 0.0f) : qsave[l - 1];
            if (l >= 2) qsave[l - 1] = qvPrev;      // delayed save (read-before-write)
            float qv;
            if (qvalid) {
                const float uR = su[l - 1][t & 1][tid + 1];
                float gy = uY[l - 1] - uZ[l - 1];
                float gx = uR - uZ[l - 1];
                qv = fmaxf(qbase - 0.5f * (gy * v1h[l] + gx * v0h[l]), 0.0f);
            } else {
                qv = 0.0f;
            }

            if (l < D) {
                float p0p = v0h[l] * qv;
                float p1p = v1h[l] * qv;
                sp[l & 1][tid + 1] = p0p;
                __syncthreads();                   // barrier level l
                const int ulo = imax(r0 - (D - 1 - l) - HALO, 0);
                if (t >= ulo) {
                    float pm1 = sp[l & 1][tid];
                    float nu = (t <= IMG_H - 1)
                        ? sig2(oh[l] - (p1p - p1prev[l] + p0p - pm1)) : 0.0f;
                    uZ[l] = uY[l]; uY[l] = nu;
                    su[l][t & 1][tid] = nu;
                }
                p1prev[l] = p1p;
            } else {
                if constexpr (FINAL) {
                    float p0p = v0h[D] * qv;
                    float p1p = v1h[D] * qv;
                    sp[D & 1][tid + 1] = p0p;
                    __syncthreads();               // barrier final
                    if (t >= r0 && t < r0 + RPB) {
                        float pm1 = sp[D & 1][tid];
                        float Tq = p1p - p1prev[D] + p0p - pm1;
                        out[ibase + (size_t)t * IMG_W + tid] = 2.0f * (oh[D] - Tq);
                    }
                    p1prev[D] = p1p;
                } else {
                    if (t >= r0 && t < r0 + RPB)
                        out[ibase + (size_t)t * IMG_W + tid] = qv;
                }
            }
            qvPrev = qv;
        }
    }
}

extern "C" void kernel_launch(void* const* d_in, const int* in_sizes, int n_in,
                              void* d_out, int out_size, void* d_ws, size_t ws_size,
                              hipStream_t stream) {
    const float* o  = (const float*)d_in[0];
    const float* vf = (const float*)d_in[1];
    float* qA = (float*)d_ws;

    // iterations 1..5: o,vf -> q5  (no q read)
    k_pipe<5, false, false><<<NBLK, TPB, 0, stream>>>(o, vf, o, qA);
    // iterations 6..10 + final: q5,o,vf -> out
    k_pipe<5, true,  true ><<<NBLK, TPB, 0, stream>>>(qA, vf, o, (float*)d_out);
}